// Round 7
// baseline (299.086 us; speedup 1.0000x reference)
//
#include <hip/hip_runtime.h>
#include <stdint.h>

typedef __bf16 bf16_t;
typedef __bf16 bf16x8 __attribute__((ext_vector_type(8)));
typedef float f32x4 __attribute__((ext_vector_type(4)));
typedef unsigned short us16x8 __attribute__((ext_vector_type(8)));

#define MFMA16(a, b, c) __builtin_amdgcn_mfma_f32_16x16x32_bf16(a, b, c, 0, 0, 0)
#define BAR() __builtin_amdgcn_s_barrier()
#define PRIO1() __builtin_amdgcn_s_setprio(1)
#define PRIO0() __builtin_amdgcn_s_setprio(0)
#define LGKM0()                                        \
  do {                                                 \
    asm volatile("s_waitcnt lgkmcnt(0)" ::: "memory"); \
    __builtin_amdgcn_sched_barrier(0);                 \
  } while (0)
#define VMCNT(n)                                          \
  do {                                                    \
    asm volatile("s_waitcnt vmcnt(" #n ")" ::: "memory"); \
    __builtin_amdgcn_sched_barrier(0);                    \
  } while (0)

__device__ __forceinline__ void stage16(const bf16_t* g, bf16_t* l) {
  __builtin_amdgcn_global_load_lds((__attribute__((address_space(1))) void*)g,
                                   (__attribute__((address_space(3))) void*)l, 16, 0, 0);
}

// ---------------- f32 -> bf16 conversion ----------------
__global__ __launch_bounds__(256) void cvt_f32_to_bf16(const float* __restrict__ in,
                                                       bf16_t* __restrict__ out, int n8) {
  int i = blockIdx.x * 256 + threadIdx.x;
  if (i >= n8) return;
  const f32x4* p = (const f32x4*)(in + (size_t)i * 8);
  f32x4 a = p[0], b = p[1];
  bf16x8 o;
  o[0] = (bf16_t)a[0]; o[1] = (bf16_t)a[1]; o[2] = (bf16_t)a[2]; o[3] = (bf16_t)a[3];
  o[4] = (bf16_t)b[0]; o[5] = (bf16_t)b[1]; o[6] = (bf16_t)b[2]; o[7] = (bf16_t)b[3];
  *(bf16x8*)(out + (size_t)i * 8) = o;
}

// ====== 128x128-tile BK=32 NT GEMM, triple-buffer, 1 phase/K-tile, 3 blocks/CU ======
// C[M,N] = A[M,K]*B[N,K]^T + bias. 256 thr = 4 waves (2Mx2N), wave 64x64, acc[4][4].
// LDS: SA[3][128][32] + SB[3][128][32] = 48 KB -> 3 blocks/CU (launch_bounds 256,3).
// Per K-tile (one phase, m201 density): 4 stage16 (tile t+2 -> buf[(t+2)%3]),
// 8 ds_read_b128 (buf[t%3]), VMCNT(4), BAR, LGKM0, 16 MFMA, BAR.
// Liveness: buf[(t+2)%3]'s last readers (tile t-1) completed (LGKM0) before tile
// t-1's end-BAR < stage issue at tile t -> race-free. VMCNT(4): outstanding after
// stage = {t+1, t+2} batches (4 each); waits t+1 (read next tile), keeps 4 in flight.
// LDS swizzle (r5-verified, 0 conflicts): 16B-block ^= (row>>1)&3, applied on the
// pre-swizzled GLOBAL source (DMA dst stays linear) and on the ds_read address.
// Requires K=2048 (nk=64 = 1 + 3*21 for the triple-unrolled loop).
template <int OUT_BF16>
__global__ __launch_bounds__(256, 3) void gemm_tb3(const bf16_t* __restrict__ A,
                                                   const bf16_t* __restrict__ B,
                                                   const float* __restrict__ bias,
                                                   void* __restrict__ Cout,
                                                   int M, int N, int K) {
  __shared__ bf16_t SA[3 * 128 * 32];
  __shared__ bf16_t SB[3 * 128 * 32];
  const int tid = threadIdx.x;
  const int l = tid & 63, w = tid >> 6;
  const int l15 = l & 15, l4 = l >> 4;
  const int wm = w >> 1, wn = w & 1;
  const int nbm = M >> 7;
  const int nwg = gridDim.x;
  const int bid = blockIdx.x;
  const int wg = (bid & 7) * (nwg >> 3) + (bid >> 3);  // XCD chunks (nwg % 8 == 0)
  const int bn = wg / nbm, bm = wg % nbm;              // bm-minor: B-panel L2-resident

  // staging: thread covers chunks {tid, 256+tid} = rows {tid>>2, 64+(tid>>2)},
  // 16B-block tid&3; source col pre-swizzled by (row>>1)&3 (same for row, row+64).
  const int r0 = tid >> 2;
  const int sc = (((tid & 3) ^ ((r0 >> 1) & 3)) << 3);
  const bf16_t* gA = A + (size_t)(bm * 128 + r0) * K + sc;
  const bf16_t* gB = B + (size_t)(bn * 128 + r0) * K + sc;
  const size_t rowK64 = (size_t)64 * K;

  // swizzled read offsets: row = {wm|wn}*64 + i*16 + l15, block = l4 ^ ((l15>>1)&3)
  const int swz = (l4 ^ ((l15 >> 1) & 3)) << 3;
  int aoff[4], boff[4];
#pragma unroll
  for (int i = 0; i < 4; ++i) {
    aoff[i] = (wm * 64 + i * 16 + l15) * 32 + swz;
    boff[i] = (wn * 64 + i * 16 + l15) * 32 + swz;
  }

  f32x4 acc[4][4] = {};
  const int nk = K >> 5;  // 64

  auto STAGE = [&](int t2, int buf) {
    const size_t ko = (size_t)t2 * 32;
    stage16(gA + ko, SA + buf * 4096 + tid * 8);
    stage16(gA + rowK64 + ko, SA + buf * 4096 + 2048 + tid * 8);
    stage16(gB + ko, SB + buf * 4096 + tid * 8);
    stage16(gB + rowK64 + ko, SB + buf * 4096 + 2048 + tid * 8);
  };

  auto TILE = [&](int t, int bufR, int bufS) {
    const int t2 = (t + 2 < nk) ? t + 2 : nk - 1;
    STAGE(t2, bufS);
    bf16x8 aR[4], bR[4];
#pragma unroll
    for (int i = 0; i < 4; ++i) {
      aR[i] = *(const bf16x8*)(SA + bufR * 4096 + aoff[i]);
      bR[i] = *(const bf16x8*)(SB + bufR * 4096 + boff[i]);
    }
    VMCNT(4);
    BAR();
    LGKM0();
    PRIO1();
#pragma unroll
    for (int mi = 0; mi < 4; ++mi)
#pragma unroll
      for (int ni = 0; ni < 4; ++ni)
        acc[mi][ni] = MFMA16(aR[mi], bR[ni], acc[mi][ni]);
    PRIO0();
    BAR();
  };

  // prologue: stage tiles 0,1 -> bufs 0,1; drain tile0 (steady-state in-flight = 4)
  STAGE(0, 0);
  STAGE(1, 1);
  VMCNT(4);
  BAR();

  for (int t = 0; t < nk - 1; t += 3) {
    TILE(t, 0, 2);
    TILE(t + 1, 1, 0);
    TILE(t + 2, 2, 1);
  }
  TILE(nk - 1, 0, 2);  // 63%3==0
  VMCNT(0);

  // ---- epilogue ----
  const int rbase = bm * 128 + wm * 64 + (l4 << 2);
  const int cbase = bn * 128 + wn * 64 + l15;
#pragma unroll
  for (int ni = 0; ni < 4; ++ni) {
    float bv = bias[cbase + ni * 16];
#pragma unroll
    for (int mi = 0; mi < 4; ++mi)
#pragma unroll
      for (int r = 0; r < 4; ++r) {
        float v = acc[mi][ni][r] + bv;
        size_t off = (size_t)(rbase + mi * 16 + r) * N + (cbase + ni * 16);
        if (OUT_BF16) ((bf16_t*)Cout)[off] = (bf16_t)v;
        else ((float*)Cout)[off] = v;
      }
  }
}

// ---------------- causal flash attention (unchanged) ----------------
__global__ __launch_bounds__(256, 2) void attn_fwd(const bf16_t* __restrict__ qkv,
                                                   bf16_t* __restrict__ att) {
  __shared__ bf16_t Kt[64 * 128];
  __shared__ bf16_t Vt[128 * 64];
  __shared__ bf16_t Pw[4][16 * 64];

  int bid = blockIdx.x;
  int pair = bid >> 5, bh = bid & 31;
  int h = bh & 15, b = bh >> 4;
  int tid = threadIdx.x;
  int l = tid & 63, w = tid >> 6;
  int l15 = l & 15, l4 = l >> 4, l7 = l & 7;
  const size_t LD = 6144;
  const bf16_t* base = qkv + (size_t)b * 2048 * LD;

#pragma unroll 1
  for (int phase = 0; phase < 2; ++phase) {
    int qt = phase ? 31 - pair : pair;
    int q0 = qt << 6;
    int wq0 = q0 + w * 16;

    bf16x8 qf[4];
#pragma unroll
    for (int kk = 0; kk < 4; ++kk)
      qf[kk] = *(const bf16x8*)(base + (size_t)(wq0 + l15) * LD + h * 128 + kk * 32 + l4 * 8);

    f32x4 acc[8] = {};
    float mrow[4], lrow[4];
#pragma unroll
    for (int r = 0; r < 4; ++r) { mrow[r] = -1e30f; lrow[r] = 0.f; }

    int nkt = qt + 1;
    for (int kt = 0; kt < nkt; ++kt) {
      int kb = kt << 6;
      const bf16_t* vg = base + (size_t)kb * LD + 4096 + h * 128;
      us16x8 va[2], vb[2];
#pragma unroll
      for (int p = 0; p < 2; ++p) {
        int g = p * 256 + tid;
        int kv = (g >> 4) << 1;
        int d0 = (g & 15) << 3;
        va[p] = *(const us16x8*)(vg + (size_t)kv * LD + d0);
        vb[p] = *(const us16x8*)(vg + (size_t)(kv + 1) * LD + d0);
      }
      const bf16_t* kg = base + (size_t)kb * LD + 2048 + h * 128;
#pragma unroll
      for (int i = 0; i < 4; ++i) {
        int e = i * 256 + tid;
        int row = e >> 4, blk = e & 15;
        int src = (blk ^ (row & 7)) << 3;
        stage16(kg + (size_t)row * LD + src, Kt + e * 8);
      }
#pragma unroll
      for (int p = 0; p < 2; ++p) {
        int g = p * 256 + tid;
        int kv = (g >> 4) << 1;
        int d0 = (g & 15) << 3;
        int k8 = kv >> 3, kr = kv & 7;
#pragma unroll
        for (int j = 0; j < 8; ++j) {
          int d = d0 + j;
          int swz = k8 ^ ((d ^ (d >> 3)) & 7);
          unsigned pack = (unsigned)va[p][j] | ((unsigned)vb[p][j] << 16);
          *(unsigned*)(&Vt[d * 64 + swz * 8 + kr]) = pack;
        }
      }
      __syncthreads();

      {
        f32x4 s[4] = {};
        __builtin_amdgcn_s_setprio(1);
#pragma unroll
        for (int kk = 0; kk < 4; ++kk) {
          int blk = (kk * 4 + l4) ^ l7;
#pragma unroll
          for (int n = 0; n < 4; ++n) {
            bf16x8 kf = *(const bf16x8*)(Kt + (n * 16 + l15) * 128 + blk * 8);
            s[n] = MFMA16(qf[kk], kf, s[n]);
          }
        }
        __builtin_amdgcn_s_setprio(0);

        const float sc = 0.08838834764831845f;
        bool needMask = (kb + 63) > wq0;
        float scf[4];
#pragma unroll
        for (int r = 0; r < 4; ++r) {
          int q = wq0 + (l4 << 2) + r;
#pragma unroll
          for (int n = 0; n < 4; ++n) {
            float v = s[n][r] * sc;
            if (needMask && (kb + n * 16 + l15) > q) v = -1e30f;
            s[n][r] = v;
          }
          float mx = fmaxf(fmaxf(s[0][r], s[1][r]), fmaxf(s[2][r], s[3][r]));
          mx = fmaxf(mx, __shfl_xor(mx, 1));
          mx = fmaxf(mx, __shfl_xor(mx, 2));
          mx = fmaxf(mx, __shfl_xor(mx, 4));
          mx = fmaxf(mx, __shfl_xor(mx, 8));
          float mn = fmaxf(mrow[r], mx);
          float sf = __expf(mrow[r] - mn);
          mrow[r] = mn;
          scf[r] = sf;
          float rs = 0.f;
#pragma unroll
          for (int n = 0; n < 4; ++n) {
            float pv = __expf(s[n][r] - mn);
            s[n][r] = pv;
            rs += pv;
          }
          rs += __shfl_xor(rs, 1);
          rs += __shfl_xor(rs, 2);
          rs += __shfl_xor(rs, 4);
          rs += __shfl_xor(rs, 8);
          lrow[r] = lrow[r] * sf + rs;
        }
#pragma unroll
        for (int nd = 0; nd < 8; ++nd)
#pragma unroll
          for (int r = 0; r < 4; ++r)
            acc[nd][r] *= scf[r];
#pragma unroll
        for (int n = 0; n < 4; ++n) {
          int cb8 = n * 2 + (l15 >> 3);
#pragma unroll
          for (int r = 0; r < 4; ++r) {
            int row = (l4 << 2) + r;
            Pw[w][row * 64 + ((cb8 ^ (row & 7)) << 3) + l7] = (bf16_t)s[n][r];
          }
        }
        __builtin_amdgcn_s_setprio(1);
#pragma unroll
        for (int kk2 = 0; kk2 < 2; ++kk2) {
          bf16x8 pa = *(const bf16x8*)(&Pw[w][l15 * 64 + (((kk2 * 4 + l4) ^ l7) << 3)]);
#pragma unroll
          for (int nd = 0; nd < 8; ++nd) {
            int d = nd * 16 + l15;
            int swz = (kk2 * 4 + l4) ^ ((d ^ (d >> 3)) & 7);
            bf16x8 bv = *(const bf16x8*)(&Vt[d * 64 + swz * 8]);
            acc[nd] = MFMA16(pa, bv, acc[nd]);
          }
        }
        __builtin_amdgcn_s_setprio(0);
      }
      __syncthreads();
    }

#pragma unroll
    for (int r = 0; r < 4; ++r) {
      float inv = 1.0f / lrow[r];
      size_t ro = (size_t)(b * 2048 + wq0 + (l4 << 2) + r) * 2048 + h * 128;
#pragma unroll
      for (int nd = 0; nd < 8; ++nd)
        att[ro + nd * 16 + l15] = (bf16_t)(acc[nd][r] * inv);
    }
  }
}

// ---------------- launch ----------------
extern "C" void kernel_launch(void* const* d_in, const int* in_sizes, int n_in,
                              void* d_out, int out_size, void* d_ws, size_t ws_size,
                              hipStream_t stream) {
  (void)in_sizes; (void)n_in; (void)out_size; (void)ws_size;
  const float* x = (const float*)d_in[0];
  const float* w_attn = (const float*)d_in[1];
  const float* b_attn = (const float*)d_in[2];
  const float* w_proj = (const float*)d_in[3];
  const float* b_proj = (const float*)d_in[4];
  float* out = (float*)d_out;

  char* ws = (char*)d_ws;
  bf16_t* xb  = (bf16_t*)(ws);
  bf16_t* wab = (bf16_t*)(ws + 16777216);
  bf16_t* wpb = (bf16_t*)(ws + 41943040);
  bf16_t* qkv = (bf16_t*)(ws + 50331648);
  bf16_t* att = xb;  // xb dead after GEMM1

  cvt_f32_to_bf16<<<4096, 256, 0, stream>>>(x, xb, 1048576);
  cvt_f32_to_bf16<<<6144, 256, 0, stream>>>(w_attn, wab, 1572864);
  cvt_f32_to_bf16<<<2048, 256, 0, stream>>>(w_proj, wpb, 524288);

  // qkv = x @ w_attn^T + b_attn -> bf16 [4096, 6144]  (128^2: 1536 blocks, 3/CU)
  gemm_tb3<1><<<1536, 256, 0, stream>>>(xb, wab, b_attn, qkv, 4096, 6144, 2048);

  // causal flash attention -> att bf16 [4096, 2048]
  attn_fwd<<<512, 256, 0, stream>>>(qkv, att);

  // out = att @ w_proj^T + b_proj -> f32 [4096, 2048]  (128^2: 512 blocks)
  gemm_tb3<0><<<512, 256, 0, stream>>>(att, wpb, b_proj, out, 4096, 2048, 2048);
}

// Round 8
// 288.534 us; speedup vs baseline: 1.0366x; 1.0366x over previous
//
#include <hip/hip_runtime.h>
#include <stdint.h>

typedef __bf16 bf16_t;
typedef __bf16 bf16x8 __attribute__((ext_vector_type(8)));
typedef float f32x4 __attribute__((ext_vector_type(4)));
typedef unsigned short us16x8 __attribute__((ext_vector_type(8)));

#define MFMA16(a, b, c) __builtin_amdgcn_mfma_f32_16x16x32_bf16(a, b, c, 0, 0, 0)
#define BAR() __builtin_amdgcn_s_barrier()
#define PRIO1() __builtin_amdgcn_s_setprio(1)
#define PRIO0() __builtin_amdgcn_s_setprio(0)
#define LGKM0()                                        \
  do {                                                 \
    asm volatile("s_waitcnt lgkmcnt(0)" ::: "memory"); \
    __builtin_amdgcn_sched_barrier(0);                 \
  } while (0)
#define VMCNT(n)                                          \
  do {                                                    \
    asm volatile("s_waitcnt vmcnt(" #n ")" ::: "memory"); \
    __builtin_amdgcn_sched_barrier(0);                    \
  } while (0)

__device__ __forceinline__ void stage16(const bf16_t* g, bf16_t* l) {
  __builtin_amdgcn_global_load_lds((__attribute__((address_space(1))) void*)g,
                                   (__attribute__((address_space(3))) void*)l, 16, 0, 0);
}

// ---------------- f32 -> bf16 conversion ----------------
__global__ __launch_bounds__(256) void cvt_f32_to_bf16(const float* __restrict__ in,
                                                       bf16_t* __restrict__ out, int n8) {
  int i = blockIdx.x * 256 + threadIdx.x;
  if (i >= n8) return;
  const f32x4* p = (const f32x4*)(in + (size_t)i * 8);
  f32x4 a = p[0], b = p[1];
  bf16x8 o;
  o[0] = (bf16_t)a[0]; o[1] = (bf16_t)a[1]; o[2] = (bf16_t)a[2]; o[3] = (bf16_t)a[3];
  o[4] = (bf16_t)b[0]; o[5] = (bf16_t)b[1]; o[6] = (bf16_t)b[2]; o[7] = (bf16_t)b[3];
  *(bf16x8*)(out + (size_t)i * 8) = o;
}

// ====== 256x128-tile BK=32 NT GEMM, 128x64 wave tiles, triple-buffer, 2 blocks/CU ====
// C[M,N] = A[M,K]*B[N,K]^T + bias. 256 thr = 4 waves (2Mx2N), wave tile 128x64,
// acc[8][4]. LDS: SA[3][256][32] + SB[3][128][32] = 72 KB -> 2 blocks/CU.
// LDS economy vs 64x64 wave: reads 42.7 FLOP/B (1.33x), writes 87 FLOP/B (2x) --
// this is the m201 wave shape, the lever behind its 62% MfmaUtil.
// Per K-tile (1 phase): 6 stage16 (tile t+2 -> buf[(t+2)%3]), 12 ds_read_b128
// (buf[t%3]), VMCNT(6), BAR, LGKM0, 32 MFMA, BAR.
// Liveness (r7-isomorphic): buf[(t+2)%3]'s last readers completed LGKM0 before
// tile t-1's end-BAR < stage issue at t. VMCNT(6): after stage, outstanding =
// {t+1,t+2} x 6; waits t+1's batch (read next tile), keeps 6 in flight; tile t's
// batch was drained by the VMCNT at t-1 -> reads safe. Never drains to 0.
// Swizzle: 16B-block ^= (row>>1)&3, pre-swizzled global source + swizzled ds_read
// ((row>>1)&3 == (l15>>1)&3 since wave row-bases are multiples of 8). 0-conflict
// (r5/r7-verified pattern).
template <int OUT_BF16>
__global__ __launch_bounds__(256, 2) void gemm_w128(const bf16_t* __restrict__ A,
                                                    const bf16_t* __restrict__ B,
                                                    const float* __restrict__ bias,
                                                    void* __restrict__ Cout,
                                                    int M, int N, int K) {
  __shared__ bf16_t SA[3 * 256 * 32];
  __shared__ bf16_t SB[3 * 128 * 32];
  const int tid = threadIdx.x;
  const int l = tid & 63, w = tid >> 6;
  const int l15 = l & 15, l4 = l >> 4;
  const int wm = w >> 1, wn = w & 1;
  const int nbn = N >> 7;  // 128-col tiles
  // XCD chunking: chunk c owns bn in [c*nbn/8, (c+1)*nbn/8), all bm; bn-minor so
  // each 1MB A-panel stays L2-hot across its chunk-local bn sweep; 3MB B-panel
  // resident for the whole chunk.
  const int c = blockIdx.x & 7, r = blockIdx.x >> 3;
  const int bnpc = nbn >> 3;
  const int bm = r / bnpc;
  const int bn = c * bnpc + r % bnpc;

  // staging: thread covers A rows {r0, +64, +128, +192}, B rows {r0, +64},
  // 16B-block tid&3, source col pre-swizzled ((r0+64k)>>1)&3 == (r0>>1)&3.
  const int r0 = tid >> 2;
  const int scol = (((tid & 3) ^ ((r0 >> 1) & 3)) << 3);
  const bf16_t* gA = A + (size_t)(bm * 256 + r0) * K + scol;
  const bf16_t* gB = B + (size_t)(bn * 128 + r0) * K + scol;
  const size_t K64 = (size_t)64 * K;

  // swizzled read offsets
  const int swz = (l4 ^ ((l15 >> 1) & 3)) << 3;
  int aoff[8], boff[4];
#pragma unroll
  for (int i = 0; i < 8; ++i) aoff[i] = (wm * 128 + i * 16 + l15) * 32 + swz;
#pragma unroll
  for (int i = 0; i < 4; ++i) boff[i] = (wn * 64 + i * 16 + l15) * 32 + swz;

  f32x4 acc[8][4] = {};
  const int nk = K >> 5;  // 64

  auto STAGE = [&](int t2, int buf) {
    const size_t ko = (size_t)t2 * 32;
    stage16(gA + ko, SA + buf * 8192 + tid * 8);
    stage16(gA + K64 + ko, SA + buf * 8192 + 2048 + tid * 8);
    stage16(gA + 2 * K64 + ko, SA + buf * 8192 + 4096 + tid * 8);
    stage16(gA + 3 * K64 + ko, SA + buf * 8192 + 6144 + tid * 8);
    stage16(gB + ko, SB + buf * 4096 + tid * 8);
    stage16(gB + K64 + ko, SB + buf * 4096 + 2048 + tid * 8);
  };

  auto TILE = [&](int t, int bufR, int bufS) {
    const int t2 = (t + 2 < nk) ? t + 2 : nk - 1;
    STAGE(t2, bufS);
    bf16x8 aR[8], bR[4];
#pragma unroll
    for (int i = 0; i < 8; ++i) aR[i] = *(const bf16x8*)(SA + bufR * 8192 + aoff[i]);
#pragma unroll
    for (int i = 0; i < 4; ++i) bR[i] = *(const bf16x8*)(SB + bufR * 4096 + boff[i]);
    VMCNT(6);
    BAR();
    LGKM0();
    PRIO1();
#pragma unroll
    for (int mi = 0; mi < 8; ++mi)
#pragma unroll
      for (int ni = 0; ni < 4; ++ni)
        acc[mi][ni] = MFMA16(aR[mi], bR[ni], acc[mi][ni]);
    PRIO0();
    BAR();
  };

  // prologue: stage tiles 0,1 -> bufs 0,1; drain tile0 (steady-state in-flight = 6)
  STAGE(0, 0);
  STAGE(1, 1);
  VMCNT(6);
  BAR();

  for (int t = 0; t < nk - 1; t += 3) {
    TILE(t, 0, 2);
    TILE(t + 1, 1, 0);
    TILE(t + 2, 2, 1);
  }
  TILE(nk - 1, 0, 2);  // 63%3==0
  VMCNT(0);

  // ---- epilogue ----
  const int rbase = bm * 256 + wm * 128 + (l4 << 2);
  const int cbase = bn * 128 + wn * 64 + l15;
#pragma unroll
  for (int ni = 0; ni < 4; ++ni) {
    float bv = bias[cbase + ni * 16];
#pragma unroll
    for (int mi = 0; mi < 8; ++mi)
#pragma unroll
      for (int rr = 0; rr < 4; ++rr) {
        float v = acc[mi][ni][rr] + bv;
        size_t off = (size_t)(rbase + mi * 16 + rr) * N + (cbase + ni * 16);
        if (OUT_BF16) ((bf16_t*)Cout)[off] = (bf16_t)v;
        else ((float*)Cout)[off] = v;
      }
  }
}

// ====== 128x128-tile BK=32 NT GEMM, triple-buffer, 3 blocks/CU (kept for GEMM2) ====
template <int OUT_BF16>
__global__ __launch_bounds__(256, 3) void gemm_tb3(const bf16_t* __restrict__ A,
                                                   const bf16_t* __restrict__ B,
                                                   const float* __restrict__ bias,
                                                   void* __restrict__ Cout,
                                                   int M, int N, int K) {
  __shared__ bf16_t SA[3 * 128 * 32];
  __shared__ bf16_t SB[3 * 128 * 32];
  const int tid = threadIdx.x;
  const int l = tid & 63, w = tid >> 6;
  const int l15 = l & 15, l4 = l >> 4;
  const int wm = w >> 1, wn = w & 1;
  const int nbm = M >> 7;
  const int nwg = gridDim.x;
  const int bid = blockIdx.x;
  const int wg = (bid & 7) * (nwg >> 3) + (bid >> 3);
  const int bn = wg / nbm, bm = wg % nbm;

  const int r0 = tid >> 2;
  const int sc = (((tid & 3) ^ ((r0 >> 1) & 3)) << 3);
  const bf16_t* gA = A + (size_t)(bm * 128 + r0) * K + sc;
  const bf16_t* gB = B + (size_t)(bn * 128 + r0) * K + sc;
  const size_t rowK64 = (size_t)64 * K;

  const int swz = (l4 ^ ((l15 >> 1) & 3)) << 3;
  int aoff[4], boff[4];
#pragma unroll
  for (int i = 0; i < 4; ++i) {
    aoff[i] = (wm * 64 + i * 16 + l15) * 32 + swz;
    boff[i] = (wn * 64 + i * 16 + l15) * 32 + swz;
  }

  f32x4 acc[4][4] = {};
  const int nk = K >> 5;

  auto STAGE = [&](int t2, int buf) {
    const size_t ko = (size_t)t2 * 32;
    stage16(gA + ko, SA + buf * 4096 + tid * 8);
    stage16(gA + rowK64 + ko, SA + buf * 4096 + 2048 + tid * 8);
    stage16(gB + ko, SB + buf * 4096 + tid * 8);
    stage16(gB + rowK64 + ko, SB + buf * 4096 + 2048 + tid * 8);
  };

  auto TILE = [&](int t, int bufR, int bufS) {
    const int t2 = (t + 2 < nk) ? t + 2 : nk - 1;
    STAGE(t2, bufS);
    bf16x8 aR[4], bR[4];
#pragma unroll
    for (int i = 0; i < 4; ++i) {
      aR[i] = *(const bf16x8*)(SA + bufR * 4096 + aoff[i]);
      bR[i] = *(const bf16x8*)(SB + bufR * 4096 + boff[i]);
    }
    VMCNT(4);
    BAR();
    LGKM0();
    PRIO1();
#pragma unroll
    for (int mi = 0; mi < 4; ++mi)
#pragma unroll
      for (int ni = 0; ni < 4; ++ni)
        acc[mi][ni] = MFMA16(aR[mi], bR[ni], acc[mi][ni]);
    PRIO0();
    BAR();
  };

  STAGE(0, 0);
  STAGE(1, 1);
  VMCNT(4);
  BAR();

  for (int t = 0; t < nk - 1; t += 3) {
    TILE(t, 0, 2);
    TILE(t + 1, 1, 0);
    TILE(t + 2, 2, 1);
  }
  TILE(nk - 1, 0, 2);
  VMCNT(0);

  const int rbase = bm * 128 + wm * 64 + (l4 << 2);
  const int cbase = bn * 128 + wn * 64 + l15;
#pragma unroll
  for (int ni = 0; ni < 4; ++ni) {
    float bv = bias[cbase + ni * 16];
#pragma unroll
    for (int mi = 0; mi < 4; ++mi)
#pragma unroll
      for (int r = 0; r < 4; ++r) {
        float v = acc[mi][ni][r] + bv;
        size_t off = (size_t)(rbase + mi * 16 + r) * N + (cbase + ni * 16);
        if (OUT_BF16) ((bf16_t*)Cout)[off] = (bf16_t)v;
        else ((float*)Cout)[off] = v;
      }
  }
}

// ---------------- causal flash attention (unchanged) ----------------
__global__ __launch_bounds__(256, 2) void attn_fwd(const bf16_t* __restrict__ qkv,
                                                   bf16_t* __restrict__ att) {
  __shared__ bf16_t Kt[64 * 128];
  __shared__ bf16_t Vt[128 * 64];
  __shared__ bf16_t Pw[4][16 * 64];

  int bid = blockIdx.x;
  int pair = bid >> 5, bh = bid & 31;
  int h = bh & 15, b = bh >> 4;
  int tid = threadIdx.x;
  int l = tid & 63, w = tid >> 6;
  int l15 = l & 15, l4 = l >> 4, l7 = l & 7;
  const size_t LD = 6144;
  const bf16_t* base = qkv + (size_t)b * 2048 * LD;

#pragma unroll 1
  for (int phase = 0; phase < 2; ++phase) {
    int qt = phase ? 31 - pair : pair;
    int q0 = qt << 6;
    int wq0 = q0 + w * 16;

    bf16x8 qf[4];
#pragma unroll
    for (int kk = 0; kk < 4; ++kk)
      qf[kk] = *(const bf16x8*)(base + (size_t)(wq0 + l15) * LD + h * 128 + kk * 32 + l4 * 8);

    f32x4 acc[8] = {};
    float mrow[4], lrow[4];
#pragma unroll
    for (int r = 0; r < 4; ++r) { mrow[r] = -1e30f; lrow[r] = 0.f; }

    int nkt = qt + 1;
    for (int kt = 0; kt < nkt; ++kt) {
      int kb = kt << 6;
      const bf16_t* vg = base + (size_t)kb * LD + 4096 + h * 128;
      us16x8 va[2], vb[2];
#pragma unroll
      for (int p = 0; p < 2; ++p) {
        int g = p * 256 + tid;
        int kv = (g >> 4) << 1;
        int d0 = (g & 15) << 3;
        va[p] = *(const us16x8*)(vg + (size_t)kv * LD + d0);
        vb[p] = *(const us16x8*)(vg + (size_t)(kv + 1) * LD + d0);
      }
      const bf16_t* kg = base + (size_t)kb * LD + 2048 + h * 128;
#pragma unroll
      for (int i = 0; i < 4; ++i) {
        int e = i * 256 + tid;
        int row = e >> 4, blk = e & 15;
        int src = (blk ^ (row & 7)) << 3;
        stage16(kg + (size_t)row * LD + src, Kt + e * 8);
      }
#pragma unroll
      for (int p = 0; p < 2; ++p) {
        int g = p * 256 + tid;
        int kv = (g >> 4) << 1;
        int d0 = (g & 15) << 3;
        int k8 = kv >> 3, kr = kv & 7;
#pragma unroll
        for (int j = 0; j < 8; ++j) {
          int d = d0 + j;
          int swz = k8 ^ ((d ^ (d >> 3)) & 7);
          unsigned pack = (unsigned)va[p][j] | ((unsigned)vb[p][j] << 16);
          *(unsigned*)(&Vt[d * 64 + swz * 8 + kr]) = pack;
        }
      }
      __syncthreads();

      {
        f32x4 s[4] = {};
        __builtin_amdgcn_s_setprio(1);
#pragma unroll
        for (int kk = 0; kk < 4; ++kk) {
          int blk = (kk * 4 + l4) ^ l7;
#pragma unroll
          for (int n = 0; n < 4; ++n) {
            bf16x8 kf = *(const bf16x8*)(Kt + (n * 16 + l15) * 128 + blk * 8);
            s[n] = MFMA16(qf[kk], kf, s[n]);
          }
        }
        __builtin_amdgcn_s_setprio(0);

        const float sc = 0.08838834764831845f;
        bool needMask = (kb + 63) > wq0;
        float scf[4];
#pragma unroll
        for (int r = 0; r < 4; ++r) {
          int q = wq0 + (l4 << 2) + r;
#pragma unroll
          for (int n = 0; n < 4; ++n) {
            float v = s[n][r] * sc;
            if (needMask && (kb + n * 16 + l15) > q) v = -1e30f;
            s[n][r] = v;
          }
          float mx = fmaxf(fmaxf(s[0][r], s[1][r]), fmaxf(s[2][r], s[3][r]));
          mx = fmaxf(mx, __shfl_xor(mx, 1));
          mx = fmaxf(mx, __shfl_xor(mx, 2));
          mx = fmaxf(mx, __shfl_xor(mx, 4));
          mx = fmaxf(mx, __shfl_xor(mx, 8));
          float mn = fmaxf(mrow[r], mx);
          float sf = __expf(mrow[r] - mn);
          mrow[r] = mn;
          scf[r] = sf;
          float rs = 0.f;
#pragma unroll
          for (int n = 0; n < 4; ++n) {
            float pv = __expf(s[n][r] - mn);
            s[n][r] = pv;
            rs += pv;
          }
          rs += __shfl_xor(rs, 1);
          rs += __shfl_xor(rs, 2);
          rs += __shfl_xor(rs, 4);
          rs += __shfl_xor(rs, 8);
          lrow[r] = lrow[r] * sf + rs;
        }
#pragma unroll
        for (int nd = 0; nd < 8; ++nd)
#pragma unroll
          for (int r = 0; r < 4; ++r)
            acc[nd][r] *= scf[r];
#pragma unroll
        for (int n = 0; n < 4; ++n) {
          int cb8 = n * 2 + (l15 >> 3);
#pragma unroll
          for (int r = 0; r < 4; ++r) {
            int row = (l4 << 2) + r;
            Pw[w][row * 64 + ((cb8 ^ (row & 7)) << 3) + l7] = (bf16_t)s[n][r];
          }
        }
        __builtin_amdgcn_s_setprio(1);
#pragma unroll
        for (int kk2 = 0; kk2 < 2; ++kk2) {
          bf16x8 pa = *(const bf16x8*)(&Pw[w][l15 * 64 + (((kk2 * 4 + l4) ^ l7) << 3)]);
#pragma unroll
          for (int nd = 0; nd < 8; ++nd) {
            int d = nd * 16 + l15;
            int swz = (kk2 * 4 + l4) ^ ((d ^ (d >> 3)) & 7);
            bf16x8 bv = *(const bf16x8*)(&Vt[d * 64 + swz * 8]);
            acc[nd] = MFMA16(pa, bv, acc[nd]);
          }
        }
        __builtin_amdgcn_s_setprio(0);
      }
      __syncthreads();
    }

#pragma unroll
    for (int r = 0; r < 4; ++r) {
      float inv = 1.0f / lrow[r];
      size_t ro = (size_t)(b * 2048 + wq0 + (l4 << 2) + r) * 2048 + h * 128;
#pragma unroll
      for (int nd = 0; nd < 8; ++nd)
        att[ro + nd * 16 + l15] = (bf16_t)(acc[nd][r] * inv);
    }
  }
}

// ---------------- launch ----------------
extern "C" void kernel_launch(void* const* d_in, const int* in_sizes, int n_in,
                              void* d_out, int out_size, void* d_ws, size_t ws_size,
                              hipStream_t stream) {
  (void)in_sizes; (void)n_in; (void)out_size; (void)ws_size;
  const float* x = (const float*)d_in[0];
  const float* w_attn = (const float*)d_in[1];
  const float* b_attn = (const float*)d_in[2];
  const float* w_proj = (const float*)d_in[3];
  const float* b_proj = (const float*)d_in[4];
  float* out = (float*)d_out;

  char* ws = (char*)d_ws;
  bf16_t* xb  = (bf16_t*)(ws);
  bf16_t* wab = (bf16_t*)(ws + 16777216);
  bf16_t* wpb = (bf16_t*)(ws + 41943040);
  bf16_t* qkv = (bf16_t*)(ws + 50331648);
  bf16_t* att = xb;  // xb dead after GEMM1

  cvt_f32_to_bf16<<<4096, 256, 0, stream>>>(x, xb, 1048576);
  cvt_f32_to_bf16<<<6144, 256, 0, stream>>>(w_attn, wab, 1572864);
  cvt_f32_to_bf16<<<2048, 256, 0, stream>>>(w_proj, wpb, 524288);

  // qkv = x @ w_attn^T + b_attn -> bf16 [4096, 6144]
  // 256x128 tiles: 16x48 = 768 blocks, 2/CU co-resident (streams, no lockstep tail)
  gemm_w128<1><<<768, 256, 0, stream>>>(xb, wab, b_attn, qkv, 4096, 6144, 2048);

  // causal flash attention -> att bf16 [4096, 2048]
  attn_fwd<<<512, 256, 0, stream>>>(qkv, att);

  // out = att @ w_proj^T + b_proj -> f32 [4096, 2048]  (128^2: 512 blocks, 3/CU)
  gemm_tb3<0><<<512, 256, 0, stream>>>(att, wpb, b_proj, out, 4096, 2048, 2048);
}

// Round 9
// 286.701 us; speedup vs baseline: 1.0432x; 1.0064x over previous
//
#include <hip/hip_runtime.h>
#include <stdint.h>

typedef __bf16 bf16_t;
typedef __bf16 bf16x8 __attribute__((ext_vector_type(8)));
typedef float f32x4 __attribute__((ext_vector_type(4)));
typedef unsigned short us16x8 __attribute__((ext_vector_type(8)));

#define MFMA16(a, b, c) __builtin_amdgcn_mfma_f32_16x16x32_bf16(a, b, c, 0, 0, 0)
#define BAR() __builtin_amdgcn_s_barrier()
#define PRIO1() __builtin_amdgcn_s_setprio(1)
#define PRIO0() __builtin_amdgcn_s_setprio(0)
#define LGKM0()                                        \
  do {                                                 \
    asm volatile("s_waitcnt lgkmcnt(0)" ::: "memory"); \
    __builtin_amdgcn_sched_barrier(0);                 \
  } while (0)
#define VMCNT(n)                                          \
  do {                                                    \
    asm volatile("s_waitcnt vmcnt(" #n ")" ::: "memory"); \
    __builtin_amdgcn_sched_barrier(0);                    \
  } while (0)

__device__ __forceinline__ void stage16(const bf16_t* g, bf16_t* l) {
  __builtin_amdgcn_global_load_lds((__attribute__((address_space(1))) void*)g,
                                   (__attribute__((address_space(3))) void*)l, 16, 0, 0);
}

// ---------------- f32 -> bf16 conversion ----------------
__global__ __launch_bounds__(256) void cvt_f32_to_bf16(const float* __restrict__ in,
                                                       bf16_t* __restrict__ out, int n8) {
  int i = blockIdx.x * 256 + threadIdx.x;
  if (i >= n8) return;
  const f32x4* p = (const f32x4*)(in + (size_t)i * 8);
  f32x4 a = p[0], b = p[1];
  bf16x8 o;
  o[0] = (bf16_t)a[0]; o[1] = (bf16_t)a[1]; o[2] = (bf16_t)a[2]; o[3] = (bf16_t)a[3];
  o[4] = (bf16_t)b[0]; o[5] = (bf16_t)b[1]; o[6] = (bf16_t)b[2]; o[7] = (bf16_t)b[3];
  *(bf16x8*)(out + (size_t)i * 8) = o;
}

// ====== PERSISTENT 256x128-tile BK=32 NT GEMM, 128x64 wave tiles, 2 blocks/CU ======
// Same per-tile schedule as r8 (race-audited): triple-buffer, 1 phase/K-tile,
// 6 stage16 + 12 ds_read_b128 + VMCNT(6) + 32 MFMA per phase, 0-conflict swizzle.
// NEW: grid = 512 = exactly 2 blocks/CU; each block loops wk = bid, bid+512 over
// the 768 output tiles -> no half-empty rounds (r4/r8 lost 1.33-1.5x to the tail).
// Blocks b and b+512 share (wk&7) -> same XCD chunk -> B-panel stays L2-resident.
// Inter-tile handoff: final TILE's end-BAR completes all LDS reads; VMCNT(0)
// drains all DMA (incl. clamped dup-stages) before the next tile's prologue.
template <int OUT_BF16>
__global__ __launch_bounds__(256, 2) void gemm_w128p(const bf16_t* __restrict__ A,
                                                     const bf16_t* __restrict__ B,
                                                     const float* __restrict__ bias,
                                                     void* __restrict__ Cout,
                                                     int M, int N, int K) {
  __shared__ bf16_t SA[3 * 256 * 32];
  __shared__ bf16_t SB[3 * 128 * 32];
  const int tid = threadIdx.x;
  const int l = tid & 63, w = tid >> 6;
  const int l15 = l & 15, l4 = l >> 4;
  const int wm = w >> 1, wn = w & 1;
  const int nbn = N >> 7;         // 128-col tiles (48)
  const int nbm = M >> 8;         // 256-row tiles (16)
  const int total = nbm * nbn;    // 768
  const int bnpc = nbn >> 3;      // 6 bn per XCD chunk

  // staging source pattern (tile-independent parts)
  const int r0 = tid >> 2;
  const int scol = (((tid & 3) ^ ((r0 >> 1) & 3)) << 3);
  const size_t K64 = (size_t)64 * K;

  // swizzled read offsets (tile-independent)
  const int swz = (l4 ^ ((l15 >> 1) & 3)) << 3;
  int aoff[8], boff[4];
#pragma unroll
  for (int i = 0; i < 8; ++i) aoff[i] = (wm * 128 + i * 16 + l15) * 32 + swz;
#pragma unroll
  for (int i = 0; i < 4; ++i) boff[i] = (wn * 64 + i * 16 + l15) * 32 + swz;

  const int nk = K >> 5;  // 64

  for (int wk = blockIdx.x; wk < total; wk += gridDim.x) {
    const int c = wk & 7, rr0 = wk >> 3;
    const int bm = rr0 / bnpc;
    const int bn = c * bnpc + rr0 % bnpc;

    const bf16_t* gA = A + (size_t)(bm * 256 + r0) * K + scol;
    const bf16_t* gB = B + (size_t)(bn * 128 + r0) * K + scol;

    f32x4 acc[8][4] = {};

    auto STAGE = [&](int t2, int buf) {
      const size_t ko = (size_t)t2 * 32;
      stage16(gA + ko, SA + buf * 8192 + tid * 8);
      stage16(gA + K64 + ko, SA + buf * 8192 + 2048 + tid * 8);
      stage16(gA + 2 * K64 + ko, SA + buf * 8192 + 4096 + tid * 8);
      stage16(gA + 3 * K64 + ko, SA + buf * 8192 + 6144 + tid * 8);
      stage16(gB + ko, SB + buf * 4096 + tid * 8);
      stage16(gB + K64 + ko, SB + buf * 4096 + 2048 + tid * 8);
    };

    auto TILE = [&](int t, int bufR, int bufS) {
      const int t2 = (t + 2 < nk) ? t + 2 : nk - 1;
      STAGE(t2, bufS);
      bf16x8 aR[8], bR[4];
#pragma unroll
      for (int i = 0; i < 8; ++i) aR[i] = *(const bf16x8*)(SA + bufR * 8192 + aoff[i]);
#pragma unroll
      for (int i = 0; i < 4; ++i) bR[i] = *(const bf16x8*)(SB + bufR * 4096 + boff[i]);
      VMCNT(6);
      BAR();
      LGKM0();
      PRIO1();
#pragma unroll
      for (int mi = 0; mi < 8; ++mi)
#pragma unroll
        for (int ni = 0; ni < 4; ++ni)
          acc[mi][ni] = MFMA16(aR[mi], bR[ni], acc[mi][ni]);
      PRIO0();
      BAR();
    };

    // prologue: stage tiles 0,1 -> bufs 0,1; drain tile0 (steady-state in-flight 6)
    STAGE(0, 0);
    STAGE(1, 1);
    VMCNT(6);
    BAR();

    for (int t = 0; t < nk - 1; t += 3) {
      TILE(t, 0, 2);
      TILE(t + 1, 1, 0);
      TILE(t + 2, 2, 1);
    }
    TILE(nk - 1, 0, 2);  // 63%3==0
    VMCNT(0);            // drain DMA (incl. dup-stages) before LDS reuse / next tile

    // ---- epilogue ----
    const int rbase = bm * 256 + wm * 128 + (l4 << 2);
    const int cbase = bn * 128 + wn * 64 + l15;
#pragma unroll
    for (int ni = 0; ni < 4; ++ni) {
      float bv = bias[cbase + ni * 16];
#pragma unroll
      for (int mi = 0; mi < 8; ++mi)
#pragma unroll
        for (int rr = 0; rr < 4; ++rr) {
          float v = acc[mi][ni][rr] + bv;
          size_t off = (size_t)(rbase + mi * 16 + rr) * N + (cbase + ni * 16);
          if (OUT_BF16) ((bf16_t*)Cout)[off] = (bf16_t)v;
          else ((float*)Cout)[off] = v;
        }
    }
  }
}

// ====== 128x128-tile BK=32 NT GEMM, triple-buffer, 3 blocks/CU (GEMM2) ====
template <int OUT_BF16>
__global__ __launch_bounds__(256, 3) void gemm_tb3(const bf16_t* __restrict__ A,
                                                   const bf16_t* __restrict__ B,
                                                   const float* __restrict__ bias,
                                                   void* __restrict__ Cout,
                                                   int M, int N, int K) {
  __shared__ bf16_t SA[3 * 128 * 32];
  __shared__ bf16_t SB[3 * 128 * 32];
  const int tid = threadIdx.x;
  const int l = tid & 63, w = tid >> 6;
  const int l15 = l & 15, l4 = l >> 4;
  const int wm = w >> 1, wn = w & 1;
  const int nbm = M >> 7;
  const int nwg = gridDim.x;
  const int bid = blockIdx.x;
  const int wg = (bid & 7) * (nwg >> 3) + (bid >> 3);
  const int bn = wg / nbm, bm = wg % nbm;

  const int r0 = tid >> 2;
  const int sc = (((tid & 3) ^ ((r0 >> 1) & 3)) << 3);
  const bf16_t* gA = A + (size_t)(bm * 128 + r0) * K + sc;
  const bf16_t* gB = B + (size_t)(bn * 128 + r0) * K + sc;
  const size_t rowK64 = (size_t)64 * K;

  const int swz = (l4 ^ ((l15 >> 1) & 3)) << 3;
  int aoff[4], boff[4];
#pragma unroll
  for (int i = 0; i < 4; ++i) {
    aoff[i] = (wm * 64 + i * 16 + l15) * 32 + swz;
    boff[i] = (wn * 64 + i * 16 + l15) * 32 + swz;
  }

  f32x4 acc[4][4] = {};
  const int nk = K >> 5;

  auto STAGE = [&](int t2, int buf) {
    const size_t ko = (size_t)t2 * 32;
    stage16(gA + ko, SA + buf * 4096 + tid * 8);
    stage16(gA + rowK64 + ko, SA + buf * 4096 + 2048 + tid * 8);
    stage16(gB + ko, SB + buf * 4096 + tid * 8);
    stage16(gB + rowK64 + ko, SB + buf * 4096 + 2048 + tid * 8);
  };

  auto TILE = [&](int t, int bufR, int bufS) {
    const int t2 = (t + 2 < nk) ? t + 2 : nk - 1;
    STAGE(t2, bufS);
    bf16x8 aR[4], bR[4];
#pragma unroll
    for (int i = 0; i < 4; ++i) {
      aR[i] = *(const bf16x8*)(SA + bufR * 4096 + aoff[i]);
      bR[i] = *(const bf16x8*)(SB + bufR * 4096 + boff[i]);
    }
    VMCNT(4);
    BAR();
    LGKM0();
    PRIO1();
#pragma unroll
    for (int mi = 0; mi < 4; ++mi)
#pragma unroll
      for (int ni = 0; ni < 4; ++ni)
        acc[mi][ni] = MFMA16(aR[mi], bR[ni], acc[mi][ni]);
    PRIO0();
    BAR();
  };

  STAGE(0, 0);
  STAGE(1, 1);
  VMCNT(4);
  BAR();

  for (int t = 0; t < nk - 1; t += 3) {
    TILE(t, 0, 2);
    TILE(t + 1, 1, 0);
    TILE(t + 2, 2, 1);
  }
  TILE(nk - 1, 0, 2);
  VMCNT(0);

  const int rbase = bm * 128 + wm * 64 + (l4 << 2);
  const int cbase = bn * 128 + wn * 64 + l15;
#pragma unroll
  for (int ni = 0; ni < 4; ++ni) {
    float bv = bias[cbase + ni * 16];
#pragma unroll
    for (int mi = 0; mi < 4; ++mi)
#pragma unroll
      for (int r = 0; r < 4; ++r) {
        float v = acc[mi][ni][r] + bv;
        size_t off = (size_t)(rbase + mi * 16 + r) * N + (cbase + ni * 16);
        if (OUT_BF16) ((bf16_t*)Cout)[off] = (bf16_t)v;
        else ((float*)Cout)[off] = v;
      }
  }
}

// ---------------- causal flash attention (unchanged) ----------------
__global__ __launch_bounds__(256, 2) void attn_fwd(const bf16_t* __restrict__ qkv,
                                                   bf16_t* __restrict__ att) {
  __shared__ bf16_t Kt[64 * 128];
  __shared__ bf16_t Vt[128 * 64];
  __shared__ bf16_t Pw[4][16 * 64];

  int bid = blockIdx.x;
  int pair = bid >> 5, bh = bid & 31;
  int h = bh & 15, b = bh >> 4;
  int tid = threadIdx.x;
  int l = tid & 63, w = tid >> 6;
  int l15 = l & 15, l4 = l >> 4, l7 = l & 7;
  const size_t LD = 6144;
  const bf16_t* base = qkv + (size_t)b * 2048 * LD;

#pragma unroll 1
  for (int phase = 0; phase < 2; ++phase) {
    int qt = phase ? 31 - pair : pair;
    int q0 = qt << 6;
    int wq0 = q0 + w * 16;

    bf16x8 qf[4];
#pragma unroll
    for (int kk = 0; kk < 4; ++kk)
      qf[kk] = *(const bf16x8*)(base + (size_t)(wq0 + l15) * LD + h * 128 + kk * 32 + l4 * 8);

    f32x4 acc[8] = {};
    float mrow[4], lrow[4];
#pragma unroll
    for (int r = 0; r < 4; ++r) { mrow[r] = -1e30f; lrow[r] = 0.f; }

    int nkt = qt + 1;
    for (int kt = 0; kt < nkt; ++kt) {
      int kb = kt << 6;
      const bf16_t* vg = base + (size_t)kb * LD + 4096 + h * 128;
      us16x8 va[2], vb[2];
#pragma unroll
      for (int p = 0; p < 2; ++p) {
        int g = p * 256 + tid;
        int kv = (g >> 4) << 1;
        int d0 = (g & 15) << 3;
        va[p] = *(const us16x8*)(vg + (size_t)kv * LD + d0);
        vb[p] = *(const us16x8*)(vg + (size_t)(kv + 1) * LD + d0);
      }
      const bf16_t* kg = base + (size_t)kb * LD + 2048 + h * 128;
#pragma unroll
      for (int i = 0; i < 4; ++i) {
        int e = i * 256 + tid;
        int row = e >> 4, blk = e & 15;
        int src = (blk ^ (row & 7)) << 3;
        stage16(kg + (size_t)row * LD + src, Kt + e * 8);
      }
#pragma unroll
      for (int p = 0; p < 2; ++p) {
        int g = p * 256 + tid;
        int kv = (g >> 4) << 1;
        int d0 = (g & 15) << 3;
        int k8 = kv >> 3, kr = kv & 7;
#pragma unroll
        for (int j = 0; j < 8; ++j) {
          int d = d0 + j;
          int swz = k8 ^ ((d ^ (d >> 3)) & 7);
          unsigned pack = (unsigned)va[p][j] | ((unsigned)vb[p][j] << 16);
          *(unsigned*)(&Vt[d * 64 + swz * 8 + kr]) = pack;
        }
      }
      __syncthreads();

      {
        f32x4 s[4] = {};
        __builtin_amdgcn_s_setprio(1);
#pragma unroll
        for (int kk = 0; kk < 4; ++kk) {
          int blk = (kk * 4 + l4) ^ l7;
#pragma unroll
          for (int n = 0; n < 4; ++n) {
            bf16x8 kf = *(const bf16x8*)(Kt + (n * 16 + l15) * 128 + blk * 8);
            s[n] = MFMA16(qf[kk], kf, s[n]);
          }
        }
        __builtin_amdgcn_s_setprio(0);

        const float sc = 0.08838834764831845f;
        bool needMask = (kb + 63) > wq0;
        float scf[4];
#pragma unroll
        for (int r = 0; r < 4; ++r) {
          int q = wq0 + (l4 << 2) + r;
#pragma unroll
          for (int n = 0; n < 4; ++n) {
            float v = s[n][r] * sc;
            if (needMask && (kb + n * 16 + l15) > q) v = -1e30f;
            s[n][r] = v;
          }
          float mx = fmaxf(fmaxf(s[0][r], s[1][r]), fmaxf(s[2][r], s[3][r]));
          mx = fmaxf(mx, __shfl_xor(mx, 1));
          mx = fmaxf(mx, __shfl_xor(mx, 2));
          mx = fmaxf(mx, __shfl_xor(mx, 4));
          mx = fmaxf(mx, __shfl_xor(mx, 8));
          float mn = fmaxf(mrow[r], mx);
          float sf = __expf(mrow[r] - mn);
          mrow[r] = mn;
          scf[r] = sf;
          float rs = 0.f;
#pragma unroll
          for (int n = 0; n < 4; ++n) {
            float pv = __expf(s[n][r] - mn);
            s[n][r] = pv;
            rs += pv;
          }
          rs += __shfl_xor(rs, 1);
          rs += __shfl_xor(rs, 2);
          rs += __shfl_xor(rs, 4);
          rs += __shfl_xor(rs, 8);
          lrow[r] = lrow[r] * sf + rs;
        }
#pragma unroll
        for (int nd = 0; nd < 8; ++nd)
#pragma unroll
          for (int r = 0; r < 4; ++r)
            acc[nd][r] *= scf[r];
#pragma unroll
        for (int n = 0; n < 4; ++n) {
          int cb8 = n * 2 + (l15 >> 3);
#pragma unroll
          for (int r = 0; r < 4; ++r) {
            int row = (l4 << 2) + r;
            Pw[w][row * 64 + ((cb8 ^ (row & 7)) << 3) + l7] = (bf16_t)s[n][r];
          }
        }
        __builtin_amdgcn_s_setprio(1);
#pragma unroll
        for (int kk2 = 0; kk2 < 2; ++kk2) {
          bf16x8 pa = *(const bf16x8*)(&Pw[w][l15 * 64 + (((kk2 * 4 + l4) ^ l7) << 3)]);
#pragma unroll
          for (int nd = 0; nd < 8; ++nd) {
            int d = nd * 16 + l15;
            int swz = (kk2 * 4 + l4) ^ ((d ^ (d >> 3)) & 7);
            bf16x8 bv = *(const bf16x8*)(&Vt[d * 64 + swz * 8]);
            acc[nd] = MFMA16(pa, bv, acc[nd]);
          }
        }
        __builtin_amdgcn_s_setprio(0);
      }
      __syncthreads();
    }

#pragma unroll
    for (int r = 0; r < 4; ++r) {
      float inv = 1.0f / lrow[r];
      size_t ro = (size_t)(b * 2048 + wq0 + (l4 << 2) + r) * 2048 + h * 128;
#pragma unroll
      for (int nd = 0; nd < 8; ++nd)
        att[ro + nd * 16 + l15] = (bf16_t)(acc[nd][r] * inv);
    }
  }
}

// ---------------- launch ----------------
extern "C" void kernel_launch(void* const* d_in, const int* in_sizes, int n_in,
                              void* d_out, int out_size, void* d_ws, size_t ws_size,
                              hipStream_t stream) {
  (void)in_sizes; (void)n_in; (void)out_size; (void)ws_size;
  const float* x = (const float*)d_in[0];
  const float* w_attn = (const float*)d_in[1];
  const float* b_attn = (const float*)d_in[2];
  const float* w_proj = (const float*)d_in[3];
  const float* b_proj = (const float*)d_in[4];
  float* out = (float*)d_out;

  char* ws = (char*)d_ws;
  bf16_t* xb  = (bf16_t*)(ws);
  bf16_t* wab = (bf16_t*)(ws + 16777216);
  bf16_t* wpb = (bf16_t*)(ws + 41943040);
  bf16_t* qkv = (bf16_t*)(ws + 50331648);
  bf16_t* att = xb;  // xb dead after GEMM1

  cvt_f32_to_bf16<<<4096, 256, 0, stream>>>(x, xb, 1048576);
  cvt_f32_to_bf16<<<6144, 256, 0, stream>>>(w_attn, wab, 1572864);
  cvt_f32_to_bf16<<<2048, 256, 0, stream>>>(w_proj, wpb, 524288);

  // qkv = x @ w_attn^T + b_attn -> bf16 [4096, 6144]
  // PERSISTENT: grid 512 = exactly 2 blocks/CU; 768 tiles distributed wk += 512
  gemm_w128p<1><<<512, 256, 0, stream>>>(xb, wab, b_attn, qkv, 4096, 6144, 2048);

  // causal flash attention -> att bf16 [4096, 2048]
  attn_fwd<<<512, 256, 0, stream>>>(qkv, att);

  // out = att @ w_proj^T + b_proj -> f32 [4096, 2048]  (128^2: 512 blocks, 3/CU)
  gemm_tb3<0><<<512, 256, 0, stream>>>(att, wpb, b_proj, out, 4096, 2048, 2048);
}